// Round 7
// baseline (673.061 us; speedup 1.0000x reference)
//
#include <hip/hip_runtime.h>
#include <math.h>

#define NN 100000
#define EE 1600000
#define GG 64
#define DD 64
#define NF 128
#define EF 32
#define LVL 3
#define EPSBN 1e-5f
#define NTILES ((NN + 63) / 64)
#define NBKT 391  // ceil(NN / 256)

typedef unsigned short u16;
typedef unsigned int u32;
typedef short s4v __attribute__((ext_vector_type(4)));
typedef short bf16x8 __attribute__((ext_vector_type(8)));
typedef float f32x4 __attribute__((ext_vector_type(4)));

__device__ __forceinline__ float4 ld4(const float* p) { return *(const float4*)p; }
__device__ __forceinline__ u16 f2b(float f) {
    u32 u = __float_as_uint(f);
    return (u16)((u + 0x7FFFu + ((u >> 16) & 1u)) >> 16);
}
__device__ __forceinline__ float b2f(u16 u) { return __uint_as_float(((u32)u) << 16); }
__device__ __forceinline__ float blo(u32 u) { return __uint_as_float(u << 16); }
__device__ __forceinline__ float bhi(u32 u) { return __uint_as_float(u & 0xFFFF0000u); }

// ---------------- CSR build: two-level bucket sort ----------------
__global__ void k1b(const int* __restrict__ to, int* __restrict__ bhist) {
    __shared__ int h[NBKT];
    for (int i = threadIdx.x; i < NBKT; i += 256) h[i] = 0;
    __syncthreads();
    for (int e = blockIdx.x * 256 + threadIdx.x; e < EE; e += 256 * gridDim.x)
        atomicAdd(&h[to[e] >> 8], 1);
    __syncthreads();
    for (int i = threadIdx.x; i < NBKT; i += 256)
        if (h[i]) atomicAdd(&bhist[i], h[i]);
}

__global__ void k1c(const int* __restrict__ bhist, int* __restrict__ bbase,
                    int* __restrict__ gcur) {
    __shared__ int s[512];
    int t = threadIdx.x;
    s[t] = (t < NBKT) ? bhist[t] : 0;
    __syncthreads();
    for (int off = 1; off < 512; off <<= 1) {
        int v = (t >= off) ? s[t - off] : 0;
        __syncthreads();
        s[t] += v;
        __syncthreads();
    }
    if (t < NBKT) {
        int base = t ? s[t - 1] : 0;
        bbase[t] = base;
        gcur[t] = base;
    }
    if (t == NBKT - 1) bbase[NBKT] = s[t];
}

// partition edges into bucket-contiguous tmp: word0 = from | (rel_to<<17), word1 = e
__global__ void k1d(const int* __restrict__ to, const int* __restrict__ from,
                    int* __restrict__ gcur, int2* __restrict__ tmp) {
    __shared__ int h[NBKT];
    __shared__ int cur[NBKT];
    for (int i = threadIdx.x; i < NBKT; i += 256) h[i] = 0;
    __syncthreads();
    for (int e = blockIdx.x * 256 + threadIdx.x; e < EE; e += 256 * gridDim.x)
        atomicAdd(&h[to[e] >> 8], 1);
    __syncthreads();
    for (int i = threadIdx.x; i < NBKT; i += 256)
        cur[i] = h[i] ? atomicAdd(&gcur[i], h[i]) : 0;
    __syncthreads();
    for (int e = blockIdx.x * 256 + threadIdx.x; e < EE; e += 256 * gridDim.x) {
        int tt = to[e];
        int b = tt >> 8;
        int pos = atomicAdd(&cur[b], 1);
        tmp[pos] = make_int2(from[e] | ((tt & 255) << 17), e);
    }
}

// per-bucket: LDS histogram+scan -> row_ptr; scatter split arrays src_s / eid_s
__global__ void kp2(const int2* __restrict__ tmp, const int* __restrict__ bbase,
                    int* __restrict__ row_ptr, int* __restrict__ src_s,
                    int* __restrict__ eid_s) {
    __shared__ int s[256];
    __shared__ int cur[256];
    int b = blockIdx.x, t = threadIdx.x;
    int e0 = bbase[b], e1 = bbase[b + 1];
    s[t] = 0;
    __syncthreads();
    for (int e = e0 + t; e < e1; e += 256) atomicAdd(&s[(tmp[e].x >> 17) & 255], 1);
    __syncthreads();
    int v = s[t];
    for (int off = 1; off < 256; off <<= 1) {
        int u = (t >= off) ? s[t - off] : 0;
        __syncthreads();
        s[t] += u;
        __syncthreads();
    }
    int excl = e0 + s[t] - v;
    cur[t] = excl;
    int n = b * 256 + t;
    if (n < NN) row_ptr[n] = excl;
    if (b == NBKT - 1 && t == 0) row_ptr[NN] = e1;
    __syncthreads();
    for (int e = e0 + t; e < e1; e += 256) {
        int2 w = tmp[e];
        int pos = atomicAdd(&cur[(w.x >> 17) & 255], 1);
        src_s[pos] = w.x & 0x1FFFF;
        eid_s[pos] = w.y;
    }
}

// ---------------- edge-feature pooling -> packed bf16 ----------------
__global__ void kpool(const float* __restrict__ ef, const int* __restrict__ row_ptr,
                      const int* __restrict__ eid_s, u16* __restrict__ pooled) {
    int lane = threadIdx.x & 63;
    int wid = threadIdx.x >> 6;
    int w = lane & 31, half = lane >> 5;
    for (int n = blockIdx.x * 4 + wid; n < NN; n += gridDim.x * 4) {
        int e0 = row_ptr[n], e1 = row_ptr[n + 1];
        float acc = 0.f;
        int e = e0 + half;
        for (; e + 6 < e1; e += 8) {
            int i0 = eid_s[e], i1 = eid_s[e + 2];
            int i2 = eid_s[e + 4], i3 = eid_s[e + 6];
            float v0 = ef[(size_t)i0 * EF + w];
            float v1 = ef[(size_t)i1 * EF + w];
            float v2 = ef[(size_t)i2 * EF + w];
            float v3 = ef[(size_t)i3 * EF + w];
            acc += (v0 + v1) + (v2 + v3);
        }
        for (; e < e1; e += 2) acc += ef[(size_t)eid_s[e] * EF + w];
        acc += __shfl_xor(acc, 32);
        if (half == 0) pooled[(size_t)n * EF + w] = f2b(acc);
    }
}

// ---------------- MFMA bf16 fused GEMM (h0 / l2) ----------------
template <int K1, int K2, bool A1BF, bool AAFF, bool EMB, bool BE, bool RESID>
__global__ __launch_bounds__(256) void kgemm_mfma(
    const void* __restrict__ A1v, const u16* __restrict__ A2,
    const float* __restrict__ W1, const float* __restrict__ W2,
    const float* __restrict__ bias, const float* __restrict__ be,
    const int* __restrict__ row_ptr, const float* __restrict__ emb,
    const int* __restrict__ nvi, const u16* __restrict__ resid,
    const float* __restrict__ raff, const float* __restrict__ aaff,
    u16* __restrict__ Xb, float* __restrict__ stats) {
    constexpr int K = K1 + K2;
    constexpr int KP = K + 8;
    __shared__ u16 A_lds[64 * KP];
    __shared__ u16 Wt_lds[64 * KP];
    __shared__ float red[128];

    const int t = threadIdx.x;
    const int lane = t & 63;
    const int wv = t >> 6;
    const int l15 = lane & 15;
    const int lg = lane >> 4;

    for (int idx = t; idx < K * 16; idx += 256) {
        int k = idx >> 4, c4 = (idx & 15) * 4;
        float4 w4 = (k < K1) ? ld4(W1 + (size_t)k * 64 + c4)
                             : ld4(W2 + (size_t)(k - K1) * 64 + c4);
        Wt_lds[(c4 + 0) * KP + k] = f2b(w4.x);
        Wt_lds[(c4 + 1) * KP + k] = f2b(w4.y);
        Wt_lds[(c4 + 2) * KP + k] = f2b(w4.z);
        Wt_lds[(c4 + 3) * KP + k] = f2b(w4.w);
    }
    if (t < 128) red[t] = 0.f;

    float bias_c[4], be_c[4], rsc_c[4], rsh_c[4];
#pragma unroll
    for (int n = 0; n < 4; n++) {
        int ch = 16 * n + l15;
        bias_c[n] = bias[ch];
        be_c[n] = BE ? be[ch] : 0.f;
        rsc_c[n] = RESID ? raff[ch] : 0.f;
        rsh_c[n] = RESID ? raff[64 + ch] : 0.f;
    }

    for (int tile = blockIdx.x; tile < NTILES; tile += gridDim.x) {
        int nb = tile * 64;
        __syncthreads();
        if (A1BF) {
            const u16* A1b = (const u16*)A1v;
            for (int idx = t; idx < 64 * (K1 / 4); idx += 256) {
                int node = idx / (K1 / 4), kq = (idx % (K1 / 4)) * 4;
                int gn = nb + node;
                s4v v = {0, 0, 0, 0};
                if (gn < NN) {
                    v = *(const s4v*)(A1b + (size_t)gn * K1 + kq);
                    if (AAFF) {
#pragma unroll
                        for (int i = 0; i < 4; i++) {
                            float f = b2f((u16)v[i]) * aaff[kq + i] + aaff[64 + kq + i];
                            v[i] = (short)f2b(f);
                        }
                    }
                }
                *(s4v*)&A_lds[node * KP + kq] = v;
            }
        } else {
            const float* A1f = (const float*)A1v;
            for (int idx = t; idx < 64 * (K1 / 4); idx += 256) {
                int node = idx / (K1 / 4), kq = (idx % (K1 / 4)) * 4;
                int gn = nb + node;
                s4v v = {0, 0, 0, 0};
                if (gn < NN) {
                    float4 a = ld4(A1f + (size_t)gn * K1 + kq);
                    v[0] = (short)f2b(a.x); v[1] = (short)f2b(a.y);
                    v[2] = (short)f2b(a.z); v[3] = (short)f2b(a.w);
                }
                *(s4v*)&A_lds[node * KP + kq] = v;
            }
        }
        if (K2 > 0) {
            for (int idx = t; idx < 64 * (K2 / 4); idx += 256) {
                int node = idx / (K2 / 4), kq = (idx % (K2 / 4)) * 4;
                int gn = nb + node;
                s4v v = {0, 0, 0, 0};
                if (gn < NN) v = *(const s4v*)(A2 + (size_t)gn * K2 + kq);
                *(s4v*)&A_lds[node * KP + K1 + kq] = v;
            }
        }
        __syncthreads();

        f32x4 acc[4];
#pragma unroll
        for (int n = 0; n < 4; n++) acc[n] = (f32x4){0.f, 0.f, 0.f, 0.f};
        const int arow = 16 * wv + l15;
#pragma unroll
        for (int kk = 0; kk < K; kk += 32) {
            s4v alo = *(const s4v*)&A_lds[arow * KP + kk + lg * 4];
            s4v ahi = *(const s4v*)&A_lds[arow * KP + kk + lg * 4 + 16];
            bf16x8 a = __builtin_shufflevector(alo, ahi, 0, 1, 2, 3, 4, 5, 6, 7);
#pragma unroll
            for (int n = 0; n < 4; n++) {
                s4v wlo = *(const s4v*)&Wt_lds[(16 * n + l15) * KP + kk + lg * 4];
                s4v whi = *(const s4v*)&Wt_lds[(16 * n + l15) * KP + kk + lg * 4 + 16];
                bf16x8 b = __builtin_shufflevector(wlo, whi, 0, 1, 2, 3, 4, 5, 6, 7);
                acc[n] = __builtin_amdgcn_mfma_f32_16x16x32_bf16(a, b, acc[n], 0, 0, 0);
            }
        }

        float ss[4] = {0, 0, 0, 0}, sq2[4] = {0, 0, 0, 0};
#pragma unroll
        for (int r = 0; r < 4; r++) {
            int node = nb + 16 * wv + lg * 4 + r;
            if (node < NN) {
                float deg = BE ? (float)(row_ptr[node + 1] - row_ptr[node]) : 0.f;
                int nv = EMB ? nvi[node] : 0;
#pragma unroll
                for (int n = 0; n < 4; n++) {
                    int ch = 16 * n + l15;
                    float v = acc[n][r] + bias_c[n];
                    if (BE) v += deg * be_c[n];
                    if (EMB) v += emb[(size_t)nv * 64 + ch];
                    if (RESID) v += b2f(resid[(size_t)node * 64 + ch]) * rsc_c[n] + rsh_c[n];
                    v = fmaxf(v, 0.f);
                    Xb[(size_t)node * 64 + ch] = f2b(v);
                    ss[n] += v;
                    sq2[n] += v * v;
                }
            }
        }
#pragma unroll
        for (int n = 0; n < 4; n++) {
            float a = ss[n];
            a += __shfl_xor(a, 16);
            a += __shfl_xor(a, 32);
            float b = sq2[n];
            b += __shfl_xor(b, 16);
            b += __shfl_xor(b, 32);
            if (lg == 0) {
                atomicAdd(&red[16 * n + l15], a);
                atomicAdd(&red[64 + 16 * n + l15], b);
            }
        }
    }
    __syncthreads();
    if (t < 128) atomicAdd(&stats[t], red[t]);
}

// ---------------- fused gather + merge GEMM ----------------
// A1 (cols 0..63)  = bn_affine(sum_{e in CSR[n]} h2[src[e]])   (gathered in-kernel)
// A2 (cols 64..95) = pooled_ef
// out = relu(A @ [cW;We] + cb + deg*be) -> bf16 mb + stats
__global__ __launch_bounds__(256) void kmerge_fused(
    const u32* __restrict__ h2, const int* __restrict__ row_ptr,
    const int* __restrict__ src_s, const u16* __restrict__ pooled,
    const float* __restrict__ cW, const float* __restrict__ We,
    const float* __restrict__ cb, const float* __restrict__ be,
    const float* __restrict__ aff, u16* __restrict__ Xb,
    float* __restrict__ stats) {
    constexpr int K = DD + EF;  // 96
    constexpr int KP = K + 8;   // 104
    __shared__ u16 A_lds[64 * KP];
    __shared__ u16 Wt_lds[64 * KP];
    __shared__ float red[128];

    const int t = threadIdx.x;
    const int lane = t & 63;
    const int wv = t >> 6;
    const int l15 = lane & 15;
    const int lg = lane >> 4;
    const int w = lane & 31, half = lane >> 5;

    for (int idx = t; idx < K * 16; idx += 256) {
        int k = idx >> 4, c4 = (idx & 15) * 4;
        float4 w4 = (k < DD) ? ld4(cW + (size_t)k * 64 + c4)
                             : ld4(We + (size_t)(k - DD) * 64 + c4);
        Wt_lds[(c4 + 0) * KP + k] = f2b(w4.x);
        Wt_lds[(c4 + 1) * KP + k] = f2b(w4.y);
        Wt_lds[(c4 + 2) * KP + k] = f2b(w4.z);
        Wt_lds[(c4 + 3) * KP + k] = f2b(w4.w);
    }
    if (t < 128) red[t] = 0.f;

    float sc0 = aff[2 * w], sc1 = aff[2 * w + 1];
    float sh0 = aff[64 + 2 * w], sh1 = aff[64 + 2 * w + 1];

    float bias_c[4], be_c[4];
#pragma unroll
    for (int n = 0; n < 4; n++) {
        int ch = 16 * n + l15;
        bias_c[n] = cb[ch];
        be_c[n] = be[ch];
    }

    for (int tile = blockIdx.x; tile < NTILES; tile += gridDim.x) {
        int nb = tile * 64;
        __syncthreads();
        // stage pooled into cols 64..95
        for (int idx = t; idx < 64 * 8; idx += 256) {
            int node = idx >> 3, kq = (idx & 7) * 4;
            int gn = nb + node;
            s4v v = {0, 0, 0, 0};
            if (gn < NN) v = *(const s4v*)(pooled + (size_t)gn * EF + kq);
            *(s4v*)&A_lds[node * KP + DD + kq] = v;
        }
        // gather h2[src] sums into cols 0..63 (wave wv -> 16 nodes)
        for (int ii = 0; ii < 16; ii++) {
            int nloc = 16 * wv + ii;
            int gn = nb + nloc;
            int e0 = 0, e1 = 0;
            if (gn < NN) { e0 = row_ptr[gn]; e1 = row_ptr[gn + 1]; }
            float a0 = 0.f, a1 = 0.f;
            int e = e0;
            for (; e + 16 <= e1; e += 16) {
                int s0 = src_s[e + half], s1 = src_s[e + 2 + half];
                int s2 = src_s[e + 4 + half], s3 = src_s[e + 6 + half];
                int s4 = src_s[e + 8 + half], s5 = src_s[e + 10 + half];
                int s6 = src_s[e + 12 + half], s7 = src_s[e + 14 + half];
                u32 u0 = h2[(size_t)s0 * 32 + w];
                u32 u1 = h2[(size_t)s1 * 32 + w];
                u32 u2 = h2[(size_t)s2 * 32 + w];
                u32 u3 = h2[(size_t)s3 * 32 + w];
                u32 u4 = h2[(size_t)s4 * 32 + w];
                u32 u5 = h2[(size_t)s5 * 32 + w];
                u32 u6 = h2[(size_t)s6 * 32 + w];
                u32 u7 = h2[(size_t)s7 * 32 + w];
                a0 += ((blo(u0) + blo(u1)) + (blo(u2) + blo(u3))) +
                      ((blo(u4) + blo(u5)) + (blo(u6) + blo(u7)));
                a1 += ((bhi(u0) + bhi(u1)) + (bhi(u2) + bhi(u3))) +
                      ((bhi(u4) + bhi(u5)) + (bhi(u6) + bhi(u7)));
            }
            for (; e + 8 <= e1; e += 8) {
                int s0 = src_s[e + half], s1 = src_s[e + 2 + half];
                int s2 = src_s[e + 4 + half], s3 = src_s[e + 6 + half];
                u32 u0 = h2[(size_t)s0 * 32 + w];
                u32 u1 = h2[(size_t)s1 * 32 + w];
                u32 u2 = h2[(size_t)s2 * 32 + w];
                u32 u3 = h2[(size_t)s3 * 32 + w];
                a0 += (blo(u0) + blo(u1)) + (blo(u2) + blo(u3));
                a1 += (bhi(u0) + bhi(u1)) + (bhi(u2) + bhi(u3));
            }
            for (; e < e1; e += 2) {
                if (e + half < e1) {
                    u32 u = h2[(size_t)src_s[e + half] * 32 + w];
                    a0 += blo(u);
                    a1 += bhi(u);
                }
            }
            a0 += __shfl_xor(a0, 32);
            a1 += __shfl_xor(a1, 32);
            if (half == 0) {
                float deg = (float)(e1 - e0);
                u16 o0 = f2b(sc0 * a0 + deg * sh0);
                u16 o1 = f2b(sc1 * a1 + deg * sh1);
                *(u32*)&A_lds[nloc * KP + 2 * w] = (u32)o0 | ((u32)o1 << 16);
            }
        }
        __syncthreads();

        f32x4 acc[4];
#pragma unroll
        for (int n = 0; n < 4; n++) acc[n] = (f32x4){0.f, 0.f, 0.f, 0.f};
        const int arow = 16 * wv + l15;
#pragma unroll
        for (int kk = 0; kk < K; kk += 32) {
            s4v alo = *(const s4v*)&A_lds[arow * KP + kk + lg * 4];
            s4v ahi = *(const s4v*)&A_lds[arow * KP + kk + lg * 4 + 16];
            bf16x8 a = __builtin_shufflevector(alo, ahi, 0, 1, 2, 3, 4, 5, 6, 7);
#pragma unroll
            for (int n = 0; n < 4; n++) {
                s4v wlo = *(const s4v*)&Wt_lds[(16 * n + l15) * KP + kk + lg * 4];
                s4v whi = *(const s4v*)&Wt_lds[(16 * n + l15) * KP + kk + lg * 4 + 16];
                bf16x8 b = __builtin_shufflevector(wlo, whi, 0, 1, 2, 3, 4, 5, 6, 7);
                acc[n] = __builtin_amdgcn_mfma_f32_16x16x32_bf16(a, b, acc[n], 0, 0, 0);
            }
        }

        float ss[4] = {0, 0, 0, 0}, sq2[4] = {0, 0, 0, 0};
#pragma unroll
        for (int r = 0; r < 4; r++) {
            int node = nb + 16 * wv + lg * 4 + r;
            if (node < NN) {
                float deg = (float)(row_ptr[node + 1] - row_ptr[node]);
#pragma unroll
                for (int n = 0; n < 4; n++) {
                    int ch = 16 * n + l15;
                    float v = acc[n][r] + bias_c[n] + deg * be_c[n];
                    v = fmaxf(v, 0.f);
                    Xb[(size_t)node * 64 + ch] = f2b(v);
                    ss[n] += v;
                    sq2[n] += v * v;
                }
            }
        }
#pragma unroll
        for (int n = 0; n < 4; n++) {
            float a = ss[n];
            a += __shfl_xor(a, 16);
            a += __shfl_xor(a, 32);
            float b = sq2[n];
            b += __shfl_xor(b, 16);
            b += __shfl_xor(b, 32);
            if (lg == 0) {
                atomicAdd(&red[16 * n + l15], a);
                atomicAdd(&red[64 + 16 * n + l15], b);
            }
        }
    }
    __syncthreads();
    if (t < 128) atomicAdd(&stats[t], red[t]);
}

// ---------------- BN finalize ----------------
__global__ void kfin(float* __restrict__ stats, const float* __restrict__ g,
                     const float* __restrict__ b, int slot) {
    int t = threadIdx.x;  // 64
    float mean = stats[t] * (1.0f / NN);
    float var = stats[64 + t] * (1.0f / NN) - mean * mean;
    float rstd = rsqrtf(fmaxf(var, 0.f) + EPSBN);
    float sc = g[t] * rstd;
    float* slotp = stats + 128 + slot * 128;
    slotp[t] = sc;
    slotp[64 + t] = b[t] - mean * sc;
    stats[t] = 0.f;
    stats[64 + t] = 0.f;
}

// ---------------- segmented max readout ----------------
__device__ __forceinline__ unsigned fenc(float f) {
    unsigned u = __float_as_uint(f);
    return (u >> 31) ? ~u : (u | 0x80000000u);
}
__device__ __forceinline__ float fdec(unsigned k) {
    return (k >> 31) ? __uint_as_float(k ^ 0x80000000u) : __uint_as_float(~k);
}

__global__ void kinitpk(unsigned* __restrict__ pk) {
    int i = blockIdx.x * blockDim.x + threadIdx.x;
    if (i < GG * DD) pk[i] = 0x007FFFFFu;
}

__global__ void kread(const u16* __restrict__ h2, const int* __restrict__ gidx,
                      const float* __restrict__ aff, unsigned* __restrict__ pk) {
    int lane = threadIdx.x & 63;
    int wid = threadIdx.x >> 6;
    float sc = aff[lane], sh = aff[64 + lane];
    int gw = blockIdx.x * 4 + wid;
    int nw = gridDim.x * 4;
    int chunk = (NN + nw - 1) / nw;
    int lo = gw * chunk, hi = min(lo + chunk, NN);
    if (lo >= hi) return;
    int cur = gidx[lo];
    float acc = -INFINITY;
    for (int n = lo; n < hi; n++) {
        int g = gidx[n];
        if (g != cur) {
            atomicMax(&pk[cur * DD + lane], fenc(acc));
            cur = g;
            acc = -INFINITY;
        }
        acc = fmaxf(acc, b2f(h2[(size_t)n * 64 + lane]) * sc + sh);
    }
    atomicMax(&pk[cur * DD + lane], fenc(acc));
}

__global__ void kout(const unsigned* __restrict__ pk, const float* __restrict__ W,
                     const float* __restrict__ b, float* __restrict__ out) {
    int t = blockIdx.x * blockDim.x + threadIdx.x;
    int g = t >> 6, d = t & 63;
    float acc = b[d];
    for (int k = 0; k < DD; k++) {
        float p = fdec(pk[g * DD + k]);
        acc += p * W[k * DD + d];
    }
    out[t] = fmaxf(acc, 0.f);
}

extern "C" void kernel_launch(void* const* d_in, const int* in_sizes, int n_in,
                              void* d_out, int out_size, void* d_ws, size_t ws_size,
                              hipStream_t stream) {
    const float* node_feat = (const float*)d_in[0];
    const float* edge_feat = (const float*)d_in[1];
    const float* w_n2l_W = (const float*)d_in[2];
    const float* w_n2l_b = (const float*)d_in[3];
    const float* nve = (const float*)d_in[4];
    const float* w_e2l_W = (const float*)d_in[5];
    const float* w_e2l_b = (const float*)d_in[6];
    const float* conv_W = (const float*)d_in[7];
    const float* conv_b = (const float*)d_in[8];
    const float* l2_W = (const float*)d_in[9];
    const float* l2_b = (const float*)d_in[10];
    const float* msg_g = (const float*)d_in[11];
    const float* msg_b = (const float*)d_in[12];
    const float* hid_g = (const float*)d_in[13];
    const float* hid_b = (const float*)d_in[14];
    const float* out_W = (const float*)d_in[15];
    const float* out_b = (const float*)d_in[16];
    const int* edge_from = (const int*)d_in[17];
    const int* edge_to = (const int*)d_in[18];
    const int* g_idx = (const int*)d_in[19];
    const int* nvi = (const int*)d_in[20];
    float* out = (float*)d_out;

    char* ws = (char*)d_ws;
    size_t off = 0;
    auto alloc = [&](size_t bytes) -> void* {
        void* p = ws + off;
        off += (bytes + 255) / 256 * 256;
        return p;
    };
    int* row_ptr = (int*)alloc((size_t)(NN + 1) * 4);
    int* src_s = (int*)alloc((size_t)EE * 4);
    int* eid_s = (int*)alloc((size_t)EE * 4);
    int2* tmp = (int2*)alloc((size_t)EE * 8);
    u16* pooled_ef = (u16*)alloc((size_t)NN * EF * 2);
    u16* h2a = (u16*)alloc((size_t)NN * DD * 2);
    u16* h2b = (u16*)alloc((size_t)NN * DD * 2);
    u16* mb_bf = (u16*)alloc((size_t)NN * DD * 2);
    float* stats = (float*)alloc(1024 * 4);
    unsigned* pk = (unsigned*)alloc((size_t)GG * DD * 4);
    int* bhist = (int*)alloc((size_t)NBKT * 4);
    int* bbase = (int*)alloc((size_t)(NBKT + 1) * 4);
    int* gcur = (int*)alloc((size_t)NBKT * 4);
    (void)ws_size; (void)n_in; (void)in_sizes; (void)out_size;

    hipMemsetAsync(bhist, 0, (size_t)NBKT * 4, stream);
    hipMemsetAsync(stats, 0, 1024 * 4, stream);
    kinitpk<<<16, 256, 0, stream>>>(pk);

    k1b<<<256, 256, 0, stream>>>(edge_to, bhist);
    k1c<<<1, 512, 0, stream>>>(bhist, bbase, gcur);
    k1d<<<256, 256, 0, stream>>>(edge_to, edge_from, gcur, tmp);
    kp2<<<NBKT, 256, 0, stream>>>(tmp, bbase, row_ptr, src_s, eid_s);
    kpool<<<2048, 256, 0, stream>>>(edge_feat, row_ptr, eid_s, pooled_ef);

    const int GB = 782;

    // h0 -> h2a
    kgemm_mfma<NF, EF, false, false, true, true, false>
        <<<GB, 256, 0, stream>>>(node_feat, pooled_ef, w_n2l_W, w_e2l_W,
                                 w_n2l_b, w_e2l_b, row_ptr, nve, nvi,
                                 nullptr, nullptr, nullptr, h2a, stats);
    kfin<<<1, 64, 0, stream>>>(stats, msg_g, msg_b, 0);

    u16* hcur = h2a;
    u16* hnext = h2b;
    for (int lv = 0; lv < LVL; lv++) {
        // fused: gather(h) + BN-affine + [agg|pooled] @ [cW;We] -> mb_bf
        kmerge_fused<<<GB, 256, 0, stream>>>(
            (const u32*)hcur, row_ptr, src_s, pooled_ef, conv_W + lv * DD * DD,
            w_e2l_W + (size_t)(lv + 1) * EF * DD, conv_b + lv * DD,
            w_e2l_b + (size_t)(lv + 1) * DD, stats + 128 + lv * 128, mb_bf, stats);
        kfin<<<1, 64, 0, stream>>>(stats, hid_g + lv * DD, hid_b + lv * DD, 4 + lv);
        kgemm_mfma<DD, 0, true, true, false, false, true>
            <<<GB, 256, 0, stream>>>(mb_bf, nullptr, l2_W + lv * DD * DD, nullptr,
                                     l2_b + lv * DD, nullptr, row_ptr, nullptr,
                                     nullptr, hcur, stats + 128 + lv * 128,
                                     stats + 128 + (4 + lv) * 128, hnext, stats);
        kfin<<<1, 64, 0, stream>>>(stats, msg_g + (lv + 1) * DD, msg_b + (lv + 1) * DD,
                                   lv + 1);
        u16* tmp2 = hcur; hcur = hnext; hnext = tmp2;
    }

    kread<<<1024, 256, 0, stream>>>(hcur, g_idx, stats + 128 + LVL * 128, pk);
    kout<<<GG, 64, 0, stream>>>(pk, out_W, out_b, out);
}

// Round 8
// 586.305 us; speedup vs baseline: 1.1480x; 1.1480x over previous
//
#include <hip/hip_runtime.h>
#include <math.h>

#define NN 100000
#define EE 1600000
#define GG 64
#define DD 64
#define NF 128
#define EF 32
#define LVL 3
#define EPSBN 1e-5f
#define NTILES ((NN + 63) / 64)
#define NBKT 391  // ceil(NN / 256)

typedef unsigned short u16;
typedef unsigned int u32;
typedef unsigned long long u64;
typedef short s4v __attribute__((ext_vector_type(4)));
typedef short bf16x8 __attribute__((ext_vector_type(8)));
typedef float f32x4 __attribute__((ext_vector_type(4)));

__device__ __forceinline__ float4 ld4(const float* p) { return *(const float4*)p; }
__device__ __forceinline__ u16 f2b(float f) {
    u32 u = __float_as_uint(f);
    return (u16)((u + 0x7FFFu + ((u >> 16) & 1u)) >> 16);
}
__device__ __forceinline__ float b2f(u16 u) { return __uint_as_float(((u32)u) << 16); }
__device__ __forceinline__ float blo(u32 u) { return __uint_as_float(u << 16); }
__device__ __forceinline__ float bhi(u32 u) { return __uint_as_float(u & 0xFFFF0000u); }

// ---------------- CSR build: two-level bucket sort ----------------
__global__ void k1b(const int* __restrict__ to, int* __restrict__ bhist) {
    __shared__ int h[NBKT];
    for (int i = threadIdx.x; i < NBKT; i += 256) h[i] = 0;
    __syncthreads();
    for (int e = blockIdx.x * 256 + threadIdx.x; e < EE; e += 256 * gridDim.x)
        atomicAdd(&h[to[e] >> 8], 1);
    __syncthreads();
    for (int i = threadIdx.x; i < NBKT; i += 256)
        if (h[i]) atomicAdd(&bhist[i], h[i]);
}

__global__ void k1c(const int* __restrict__ bhist, int* __restrict__ bbase,
                    int* __restrict__ gcur) {
    __shared__ int s[512];
    int t = threadIdx.x;
    s[t] = (t < NBKT) ? bhist[t] : 0;
    __syncthreads();
    for (int off = 1; off < 512; off <<= 1) {
        int v = (t >= off) ? s[t - off] : 0;
        __syncthreads();
        s[t] += v;
        __syncthreads();
    }
    if (t < NBKT) {
        int base = t ? s[t - 1] : 0;
        bbase[t] = base;
        gcur[t] = base;
    }
    if (t == NBKT - 1) bbase[NBKT] = s[t];
}

// partition edges into bucket-contiguous tmp: word0 = from | (rel_to<<17), word1 = e
__global__ void k1d(const int* __restrict__ to, const int* __restrict__ from,
                    int* __restrict__ gcur, int2* __restrict__ tmp) {
    __shared__ int h[NBKT];
    __shared__ int cur[NBKT];
    for (int i = threadIdx.x; i < NBKT; i += 256) h[i] = 0;
    __syncthreads();
    for (int e = blockIdx.x * 256 + threadIdx.x; e < EE; e += 256 * gridDim.x)
        atomicAdd(&h[to[e] >> 8], 1);
    __syncthreads();
    for (int i = threadIdx.x; i < NBKT; i += 256)
        cur[i] = h[i] ? atomicAdd(&gcur[i], h[i]) : 0;
    __syncthreads();
    for (int e = blockIdx.x * 256 + threadIdx.x; e < EE; e += 256 * gridDim.x) {
        int tt = to[e];
        int b = tt >> 8;
        int pos = atomicAdd(&cur[b], 1);
        tmp[pos] = make_int2(from[e] | ((tt & 255) << 17), e);
    }
}

// per-bucket: LDS histogram+scan -> row_ptr; scatter split arrays src_s / eid_s
__global__ void kp2(const int2* __restrict__ tmp, const int* __restrict__ bbase,
                    int* __restrict__ row_ptr, int* __restrict__ src_s,
                    int* __restrict__ eid_s) {
    __shared__ int s[256];
    __shared__ int cur[256];
    int b = blockIdx.x, t = threadIdx.x;
    int e0 = bbase[b], e1 = bbase[b + 1];
    s[t] = 0;
    __syncthreads();
    for (int e = e0 + t; e < e1; e += 256) atomicAdd(&s[(tmp[e].x >> 17) & 255], 1);
    __syncthreads();
    int v = s[t];
    for (int off = 1; off < 256; off <<= 1) {
        int u = (t >= off) ? s[t - off] : 0;
        __syncthreads();
        s[t] += u;
        __syncthreads();
    }
    int excl = e0 + s[t] - v;
    cur[t] = excl;
    int n = b * 256 + t;
    if (n < NN) row_ptr[n] = excl;
    if (b == NBKT - 1 && t == 0) row_ptr[NN] = e1;
    __syncthreads();
    for (int e = e0 + t; e < e1; e += 256) {
        int2 w = tmp[e];
        int pos = atomicAdd(&cur[(w.x >> 17) & 255], 1);
        src_s[pos] = w.x & 0x1FFFF;
        eid_s[pos] = w.y;
    }
}

// ---------------- edge-feature pooling -> packed bf16 ----------------
// wave per node: 4 edge-slots x 16 lanes x float2 (8B); 16 rows in flight
__global__ void kpool(const float* __restrict__ ef, const int* __restrict__ row_ptr,
                      const int* __restrict__ eid_s, u16* __restrict__ pooled) {
    int lane = threadIdx.x & 63;
    int wid = threadIdx.x >> 6;
    int w = lane & 15, slot = lane >> 4;
    for (int n = blockIdx.x * 4 + wid; n < NN; n += gridDim.x * 4) {
        int e0 = row_ptr[n], e1 = row_ptr[n + 1];
        float ax = 0.f, ay = 0.f;
        int e = e0 + slot;
        for (; e + 12 < e1; e += 16) {
            int i0 = eid_s[e], i1 = eid_s[e + 4], i2 = eid_s[e + 8], i3 = eid_s[e + 12];
            float2 v0 = *(const float2*)(ef + (size_t)i0 * EF + 2 * w);
            float2 v1 = *(const float2*)(ef + (size_t)i1 * EF + 2 * w);
            float2 v2 = *(const float2*)(ef + (size_t)i2 * EF + 2 * w);
            float2 v3 = *(const float2*)(ef + (size_t)i3 * EF + 2 * w);
            ax += (v0.x + v1.x) + (v2.x + v3.x);
            ay += (v0.y + v1.y) + (v2.y + v3.y);
        }
        for (; e < e1; e += 4) {
            float2 v = *(const float2*)(ef + (size_t)eid_s[e] * EF + 2 * w);
            ax += v.x;
            ay += v.y;
        }
        ax += __shfl_xor(ax, 16);
        ax += __shfl_xor(ax, 32);
        ay += __shfl_xor(ay, 16);
        ay += __shfl_xor(ay, 32);
        if (slot == 0) {
            u32 o = (u32)f2b(ax) | ((u32)f2b(ay) << 16);
            *(u32*)&pooled[(size_t)n * EF + 2 * w] = o;
        }
    }
}

// ---------------- MFMA bf16 fused GEMM (h0 / merge / l2) ----------------
template <int K1, int K2, bool A1BF, bool AAFF, bool EMB, bool BE, bool RESID>
__global__ __launch_bounds__(256) void kgemm_mfma(
    const void* __restrict__ A1v, const u16* __restrict__ A2,
    const float* __restrict__ W1, const float* __restrict__ W2,
    const float* __restrict__ bias, const float* __restrict__ be,
    const int* __restrict__ row_ptr, const float* __restrict__ emb,
    const int* __restrict__ nvi, const u16* __restrict__ resid,
    const float* __restrict__ raff, const float* __restrict__ aaff,
    u16* __restrict__ Xb, float* __restrict__ stats) {
    constexpr int K = K1 + K2;
    constexpr int KP = K + 8;
    __shared__ u16 A_lds[64 * KP];
    __shared__ u16 Wt_lds[64 * KP];
    __shared__ float red[128];

    const int t = threadIdx.x;
    const int lane = t & 63;
    const int wv = t >> 6;
    const int l15 = lane & 15;
    const int lg = lane >> 4;

    for (int idx = t; idx < K * 16; idx += 256) {
        int k = idx >> 4, c4 = (idx & 15) * 4;
        float4 w4 = (k < K1) ? ld4(W1 + (size_t)k * 64 + c4)
                             : ld4(W2 + (size_t)(k - K1) * 64 + c4);
        Wt_lds[(c4 + 0) * KP + k] = f2b(w4.x);
        Wt_lds[(c4 + 1) * KP + k] = f2b(w4.y);
        Wt_lds[(c4 + 2) * KP + k] = f2b(w4.z);
        Wt_lds[(c4 + 3) * KP + k] = f2b(w4.w);
    }
    if (t < 128) red[t] = 0.f;

    float bias_c[4], be_c[4], rsc_c[4], rsh_c[4];
#pragma unroll
    for (int n = 0; n < 4; n++) {
        int ch = 16 * n + l15;
        bias_c[n] = bias[ch];
        be_c[n] = BE ? be[ch] : 0.f;
        rsc_c[n] = RESID ? raff[ch] : 0.f;
        rsh_c[n] = RESID ? raff[64 + ch] : 0.f;
    }

    for (int tile = blockIdx.x; tile < NTILES; tile += gridDim.x) {
        int nb = tile * 64;
        __syncthreads();
        if (A1BF) {
            const u16* A1b = (const u16*)A1v;
            for (int idx = t; idx < 64 * (K1 / 4); idx += 256) {
                int node = idx / (K1 / 4), kq = (idx % (K1 / 4)) * 4;
                int gn = nb + node;
                s4v v = {0, 0, 0, 0};
                if (gn < NN) {
                    v = *(const s4v*)(A1b + (size_t)gn * K1 + kq);
                    if (AAFF) {
#pragma unroll
                        for (int i = 0; i < 4; i++) {
                            float f = b2f((u16)v[i]) * aaff[kq + i] + aaff[64 + kq + i];
                            v[i] = (short)f2b(f);
                        }
                    }
                }
                *(s4v*)&A_lds[node * KP + kq] = v;
            }
        } else {
            const float* A1f = (const float*)A1v;
            for (int idx = t; idx < 64 * (K1 / 4); idx += 256) {
                int node = idx / (K1 / 4), kq = (idx % (K1 / 4)) * 4;
                int gn = nb + node;
                s4v v = {0, 0, 0, 0};
                if (gn < NN) {
                    float4 a = ld4(A1f + (size_t)gn * K1 + kq);
                    v[0] = (short)f2b(a.x); v[1] = (short)f2b(a.y);
                    v[2] = (short)f2b(a.z); v[3] = (short)f2b(a.w);
                }
                *(s4v*)&A_lds[node * KP + kq] = v;
            }
        }
        if (K2 > 0) {
            for (int idx = t; idx < 64 * (K2 / 4); idx += 256) {
                int node = idx / (K2 / 4), kq = (idx % (K2 / 4)) * 4;
                int gn = nb + node;
                s4v v = {0, 0, 0, 0};
                if (gn < NN) v = *(const s4v*)(A2 + (size_t)gn * K2 + kq);
                *(s4v*)&A_lds[node * KP + K1 + kq] = v;
            }
        }
        __syncthreads();

        f32x4 acc[4];
#pragma unroll
        for (int n = 0; n < 4; n++) acc[n] = (f32x4){0.f, 0.f, 0.f, 0.f};
        const int arow = 16 * wv + l15;
#pragma unroll
        for (int kk = 0; kk < K; kk += 32) {
            s4v alo = *(const s4v*)&A_lds[arow * KP + kk + lg * 4];
            s4v ahi = *(const s4v*)&A_lds[arow * KP + kk + lg * 4 + 16];
            bf16x8 a = __builtin_shufflevector(alo, ahi, 0, 1, 2, 3, 4, 5, 6, 7);
#pragma unroll
            for (int n = 0; n < 4; n++) {
                s4v wlo = *(const s4v*)&Wt_lds[(16 * n + l15) * KP + kk + lg * 4];
                s4v whi = *(const s4v*)&Wt_lds[(16 * n + l15) * KP + kk + lg * 4 + 16];
                bf16x8 b = __builtin_shufflevector(wlo, whi, 0, 1, 2, 3, 4, 5, 6, 7);
                acc[n] = __builtin_amdgcn_mfma_f32_16x16x32_bf16(a, b, acc[n], 0, 0, 0);
            }
        }

        float ss[4] = {0, 0, 0, 0}, sq2[4] = {0, 0, 0, 0};
#pragma unroll
        for (int r = 0; r < 4; r++) {
            int node = nb + 16 * wv + lg * 4 + r;
            if (node < NN) {
                float deg = BE ? (float)(row_ptr[node + 1] - row_ptr[node]) : 0.f;
                int nv = EMB ? nvi[node] : 0;
#pragma unroll
                for (int n = 0; n < 4; n++) {
                    int ch = 16 * n + l15;
                    float v = acc[n][r] + bias_c[n];
                    if (BE) v += deg * be_c[n];
                    if (EMB) v += emb[(size_t)nv * 64 + ch];
                    if (RESID) v += b2f(resid[(size_t)node * 64 + ch]) * rsc_c[n] + rsh_c[n];
                    v = fmaxf(v, 0.f);
                    Xb[(size_t)node * 64 + ch] = f2b(v);
                    ss[n] += v;
                    sq2[n] += v * v;
                }
            }
        }
#pragma unroll
        for (int n = 0; n < 4; n++) {
            float a = ss[n];
            a += __shfl_xor(a, 16);
            a += __shfl_xor(a, 32);
            float b = sq2[n];
            b += __shfl_xor(b, 16);
            b += __shfl_xor(b, 32);
            if (lg == 0) {
                atomicAdd(&red[16 * n + l15], a);
                atomicAdd(&red[64 + 16 * n + l15], b);
            }
        }
    }
    __syncthreads();
    if (t < 128) atomicAdd(&stats[t], red[t]);
}

// ---------------- BN finalize ----------------
__global__ void kfin(float* __restrict__ stats, const float* __restrict__ g,
                     const float* __restrict__ b, int slot) {
    int t = threadIdx.x;  // 64
    float mean = stats[t] * (1.0f / NN);
    float var = stats[64 + t] * (1.0f / NN) - mean * mean;
    float rstd = rsqrtf(fmaxf(var, 0.f) + EPSBN);
    float sc = g[t] * rstd;
    float* slotp = stats + 128 + slot * 128;
    slotp[t] = sc;
    slotp[64 + t] = b[t] - mean * sc;
    stats[t] = 0.f;
    stats[64 + t] = 0.f;
}

// ---------------- message passing over packed bf16 h ----------------
// wave per node: 4 edge-slots x 16 lanes x u64 (4 bf16 ch); 16 rows in flight
__global__ void kmsg_bf(const u64* __restrict__ h4, const int* __restrict__ row_ptr,
                        const int* __restrict__ src_s, const float* __restrict__ aff,
                        u64* __restrict__ agg) {
    int lane = threadIdx.x & 63;
    int wid = threadIdx.x >> 6;
    int w = lane & 15, slot = lane >> 4;
    float sc0 = aff[4 * w], sc1 = aff[4 * w + 1];
    float sc2 = aff[4 * w + 2], sc3 = aff[4 * w + 3];
    float sh0 = aff[64 + 4 * w], sh1 = aff[64 + 4 * w + 1];
    float sh2 = aff[64 + 4 * w + 2], sh3 = aff[64 + 4 * w + 3];
    for (int n = blockIdx.x * 4 + wid; n < NN; n += gridDim.x * 4) {
        int e0 = row_ptr[n], e1 = row_ptr[n + 1];
        float a0 = 0.f, a1 = 0.f, a2 = 0.f, a3 = 0.f;
        int e = e0 + slot;
        for (; e + 12 < e1; e += 16) {
            int s0 = src_s[e], s1 = src_s[e + 4], s2 = src_s[e + 8], s3 = src_s[e + 12];
            u64 v0 = h4[(size_t)s0 * 16 + w];
            u64 v1 = h4[(size_t)s1 * 16 + w];
            u64 v2 = h4[(size_t)s2 * 16 + w];
            u64 v3 = h4[(size_t)s3 * 16 + w];
            u32 l0 = (u32)v0, h0 = (u32)(v0 >> 32);
            u32 l1 = (u32)v1, h1 = (u32)(v1 >> 32);
            u32 l2 = (u32)v2, h2w = (u32)(v2 >> 32);
            u32 l3 = (u32)v3, h3 = (u32)(v3 >> 32);
            a0 += (blo(l0) + blo(l1)) + (blo(l2) + blo(l3));
            a1 += (bhi(l0) + bhi(l1)) + (bhi(l2) + bhi(l3));
            a2 += (blo(h0) + blo(h1)) + (blo(h2w) + blo(h3));
            a3 += (bhi(h0) + bhi(h1)) + (bhi(h2w) + bhi(h3));
        }
        for (; e < e1; e += 4) {
            u64 v = h4[(size_t)src_s[e] * 16 + w];
            u32 l = (u32)v, h = (u32)(v >> 32);
            a0 += blo(l);
            a1 += bhi(l);
            a2 += blo(h);
            a3 += bhi(h);
        }
        a0 += __shfl_xor(a0, 16);
        a0 += __shfl_xor(a0, 32);
        a1 += __shfl_xor(a1, 16);
        a1 += __shfl_xor(a1, 32);
        a2 += __shfl_xor(a2, 16);
        a2 += __shfl_xor(a2, 32);
        a3 += __shfl_xor(a3, 16);
        a3 += __shfl_xor(a3, 32);
        if (slot == 0) {
            float deg = (float)(e1 - e0);
            u32 lo = (u32)f2b(sc0 * a0 + deg * sh0) | ((u32)f2b(sc1 * a1 + deg * sh1) << 16);
            u32 hi = (u32)f2b(sc2 * a2 + deg * sh2) | ((u32)f2b(sc3 * a3 + deg * sh3) << 16);
            agg[(size_t)n * 16 + w] = (u64)lo | ((u64)hi << 32);
        }
    }
}

// ---------------- segmented max readout ----------------
__device__ __forceinline__ unsigned fenc(float f) {
    unsigned u = __float_as_uint(f);
    return (u >> 31) ? ~u : (u | 0x80000000u);
}
__device__ __forceinline__ float fdec(unsigned k) {
    return (k >> 31) ? __uint_as_float(k ^ 0x80000000u) : __uint_as_float(~k);
}

__global__ void kinitpk(unsigned* __restrict__ pk) {
    int i = blockIdx.x * blockDim.x + threadIdx.x;
    if (i < GG * DD) pk[i] = 0x007FFFFFu;
}

__global__ void kread(const u16* __restrict__ h2, const int* __restrict__ gidx,
                      const float* __restrict__ aff, unsigned* __restrict__ pk) {
    int lane = threadIdx.x & 63;
    int wid = threadIdx.x >> 6;
    float sc = aff[lane], sh = aff[64 + lane];
    int gw = blockIdx.x * 4 + wid;
    int nw = gridDim.x * 4;
    int chunk = (NN + nw - 1) / nw;
    int lo = gw * chunk, hi = min(lo + chunk, NN);
    if (lo >= hi) return;
    int cur = gidx[lo];
    float acc = -INFINITY;
    for (int n = lo; n < hi; n++) {
        int g = gidx[n];
        if (g != cur) {
            atomicMax(&pk[cur * DD + lane], fenc(acc));
            cur = g;
            acc = -INFINITY;
        }
        acc = fmaxf(acc, b2f(h2[(size_t)n * 64 + lane]) * sc + sh);
    }
    atomicMax(&pk[cur * DD + lane], fenc(acc));
}

__global__ void kout(const unsigned* __restrict__ pk, const float* __restrict__ W,
                     const float* __restrict__ b, float* __restrict__ out) {
    int t = blockIdx.x * blockDim.x + threadIdx.x;
    int g = t >> 6, d = t & 63;
    float acc = b[d];
    for (int k = 0; k < DD; k++) {
        float p = fdec(pk[g * DD + k]);
        acc += p * W[k * DD + d];
    }
    out[t] = fmaxf(acc, 0.f);
}

extern "C" void kernel_launch(void* const* d_in, const int* in_sizes, int n_in,
                              void* d_out, int out_size, void* d_ws, size_t ws_size,
                              hipStream_t stream) {
    const float* node_feat = (const float*)d_in[0];
    const float* edge_feat = (const float*)d_in[1];
    const float* w_n2l_W = (const float*)d_in[2];
    const float* w_n2l_b = (const float*)d_in[3];
    const float* nve = (const float*)d_in[4];
    const float* w_e2l_W = (const float*)d_in[5];
    const float* w_e2l_b = (const float*)d_in[6];
    const float* conv_W = (const float*)d_in[7];
    const float* conv_b = (const float*)d_in[8];
    const float* l2_W = (const float*)d_in[9];
    const float* l2_b = (const float*)d_in[10];
    const float* msg_g = (const float*)d_in[11];
    const float* msg_b = (const float*)d_in[12];
    const float* hid_g = (const float*)d_in[13];
    const float* hid_b = (const float*)d_in[14];
    const float* out_W = (const float*)d_in[15];
    const float* out_b = (const float*)d_in[16];
    const int* edge_from = (const int*)d_in[17];
    const int* edge_to = (const int*)d_in[18];
    const int* g_idx = (const int*)d_in[19];
    const int* nvi = (const int*)d_in[20];
    float* out = (float*)d_out;

    char* ws = (char*)d_ws;
    size_t off = 0;
    auto alloc = [&](size_t bytes) -> void* {
        void* p = ws + off;
        off += (bytes + 255) / 256 * 256;
        return p;
    };
    int* row_ptr = (int*)alloc((size_t)(NN + 1) * 4);
    int* src_s = (int*)alloc((size_t)EE * 4);
    int* eid_s = (int*)alloc((size_t)EE * 4);
    int2* tmp = (int2*)alloc((size_t)EE * 8);
    u16* pooled_ef = (u16*)alloc((size_t)NN * EF * 2);
    u16* h2a = (u16*)alloc((size_t)NN * DD * 2);
    u16* h2b = (u16*)alloc((size_t)NN * DD * 2);
    u16* agg_bf = (u16*)alloc((size_t)NN * DD * 2);
    u16* mb_bf = (u16*)alloc((size_t)NN * DD * 2);
    float* stats = (float*)alloc(1024 * 4);
    unsigned* pk = (unsigned*)alloc((size_t)GG * DD * 4);
    int* bhist = (int*)alloc((size_t)NBKT * 4);
    int* bbase = (int*)alloc((size_t)(NBKT + 1) * 4);
    int* gcur = (int*)alloc((size_t)NBKT * 4);
    (void)ws_size; (void)n_in; (void)in_sizes; (void)out_size;

    hipMemsetAsync(bhist, 0, (size_t)NBKT * 4, stream);
    hipMemsetAsync(stats, 0, 1024 * 4, stream);
    kinitpk<<<16, 256, 0, stream>>>(pk);

    k1b<<<256, 256, 0, stream>>>(edge_to, bhist);
    k1c<<<1, 512, 0, stream>>>(bhist, bbase, gcur);
    k1d<<<256, 256, 0, stream>>>(edge_to, edge_from, gcur, tmp);
    kp2<<<NBKT, 256, 0, stream>>>(tmp, bbase, row_ptr, src_s, eid_s);
    kpool<<<4096, 256, 0, stream>>>(edge_feat, row_ptr, eid_s, pooled_ef);

    const int GB = 782;

    // h0 -> h2a
    kgemm_mfma<NF, EF, false, false, true, true, false>
        <<<GB, 256, 0, stream>>>(node_feat, pooled_ef, w_n2l_W, w_e2l_W,
                                 w_n2l_b, w_e2l_b, row_ptr, nve, nvi,
                                 nullptr, nullptr, nullptr, h2a, stats);
    kfin<<<1, 64, 0, stream>>>(stats, msg_g, msg_b, 0);

    u16* hcur = h2a;
    u16* hnext = h2b;
    for (int lv = 0; lv < LVL; lv++) {
        kmsg_bf<<<4096, 256, 0, stream>>>((const u64*)hcur, row_ptr, src_s,
                                          stats + 128 + lv * 128, (u64*)agg_bf);
        kgemm_mfma<DD, EF, true, false, false, true, false>
            <<<GB, 256, 0, stream>>>(agg_bf, pooled_ef, conv_W + lv * DD * DD,
                                     w_e2l_W + (size_t)(lv + 1) * EF * DD,
                                     conv_b + lv * DD,
                                     w_e2l_b + (size_t)(lv + 1) * DD, row_ptr,
                                     nullptr, nullptr, nullptr, nullptr, nullptr,
                                     mb_bf, stats);
        kfin<<<1, 64, 0, stream>>>(stats, hid_g + lv * DD, hid_b + lv * DD, 4 + lv);
        kgemm_mfma<DD, 0, true, true, false, false, true>
            <<<GB, 256, 0, stream>>>(mb_bf, nullptr, l2_W + lv * DD * DD, nullptr,
                                     l2_b + lv * DD, nullptr, row_ptr, nullptr,
                                     nullptr, hcur, stats + 128 + lv * 128,
                                     stats + 128 + (4 + lv) * 128, hnext, stats);
        kfin<<<1, 64, 0, stream>>>(stats, msg_g + (lv + 1) * DD, msg_b + (lv + 1) * DD,
                                   lv + 1);
        u16* tmp2 = hcur; hcur = hnext; hnext = tmp2;
    }

    kread<<<1024, 256, 0, stream>>>(hcur, g_idx, stats + 128 + LVL * 128, pk);
    kout<<<GG, 64, 0, stream>>>(pk, out_W, out_b, out);
}